// Round 14
// baseline (3575.747 us; speedup 1.0000x reference)
//
#include <hip/hip_runtime.h>
#include <stdint.h>
#include <stddef.h>

typedef __attribute__((ext_vector_type(8))) short short8;
typedef __attribute__((ext_vector_type(4))) float f32x4;
typedef __attribute__((ext_vector_type(4))) float float4v;
typedef __attribute__((ext_vector_type(4))) unsigned short us4;

#define D_    768
#define HH    12
#define DHEAD 64
#define NP    576
#define BB    16
#define MROWS 9216      // BB*NP
#define KPAT  1216      // 1200 padded to multiple of 64 (P=38 even)
#define SCL   0.18033688011112042f   // 0.125 * log2(e)

static __device__ __forceinline__ unsigned short f2bf(float f){
  union { float f; unsigned int u; } v; v.f = f;
  unsigned int u = v.u;
  return (unsigned short)((u + 0x7FFFu + ((u >> 16) & 1u)) >> 16);
}

static __device__ __forceinline__ us4 f2bf4(float4v v){
  us4 r;
  r.x = f2bf(v.x); r.y = f2bf(v.y); r.z = f2bf(v.z); r.w = f2bf(v.w);
  return r;
}

static __device__ __forceinline__ void gld16(const void* g, void* l){
  __builtin_amdgcn_global_load_lds((const __attribute__((address_space(1))) void*)g,
                                   (__attribute__((address_space(3))) void*)l,
                                   16, 0, 0);
}

static __device__ __forceinline__ void barx(){
  asm volatile("" ::: "memory");
  __builtin_amdgcn_s_barrier();
  asm volatile("" ::: "memory");
}

// ---------------- gemm3r: BM=256 BN=128, 3-slot 32-k ring, 73.7KB LDS --------
// 2 blocks/CU. 8 waves 4Mx2N, 16 MFMA/phase, ONE barrier per phase.
__global__ __launch_bounds__(512, 4) void gemm3r(
    const unsigned short* __restrict__ A,
    const unsigned short* __restrict__ W,
    const float* __restrict__ bias,
    const float* __restrict__ pos,
    const float* res,
    float* outf,
    unsigned short* outb,
    int M, int N, int K, int relu)
{
  __shared__ unsigned short sA[3][256*32];   // 48 KB
  __shared__ unsigned short sB[3][128*32];   // 24 KB
  const int NB = N >> 7;
  const int nwg = (int)gridDim.x;
  const int wid0 = (int)blockIdx.x;
  const int xcd = wid0 & 7, bidx = wid0 >> 3;
  const int q = nwg >> 3, r = nwg & 7;
  const int wid = (xcd < r ? xcd*(q+1) : r*(q+1) + (xcd-r)*q) + bidx;
  const int mb = wid / NB, nb = wid % NB;
  const int m0 = mb << 8, n0 = nb << 7;
  const int t = threadIdx.x;
  const int w = t >> 6, l = t & 63;
  const int wr = w >> 1, wc = w & 1;          // 4M x 2N wave grid
  const int fr = l & 15, fq = l >> 4;
  const int srow = l >> 2;
  const int schk = (l & 3) ^ ((l >> 3) & 3);

  const f32x4 zero = {0.f, 0.f, 0.f, 0.f};
  f32x4 acc[4][4];
  #pragma unroll
  for (int i = 0; i < 4; ++i)
    #pragma unroll
    for (int j = 0; j < 4; ++j) acc[i][j] = zero;

  const int P = K >> 5;                        // >= 3

  auto stg = [&](int h){
    const int s = h % 3;
    #pragma unroll
    for (int i = 0; i < 2; ++i){
      const int rb = i*128 + w*16;
      gld16(A + (size_t)(m0 + rb + srow) * K + (h<<5) + (schk<<3), &sA[s][rb*32]);
    }
    const int rb = w*16;
    gld16(W + (size_t)(n0 + rb + srow) * K + (h<<5) + (schk<<3), &sB[s][rb*32]);
  };

  stg(0); stg(1);
  asm volatile("s_waitcnt vmcnt(3)" ::: "memory");   // slot 0 landed
  barx();

  for (int p = 0; p < P; ++p){
    const int s = p % 3;
    short8 a[4], b[4];
    #pragma unroll
    for (int i = 0; i < 4; ++i){
      const int R = wr*64 + i*16 + fr;
      a[i] = *(const short8*)&sA[s][R*32 + ((fq ^ ((R>>1)&3))<<3)];
    }
    #pragma unroll
    for (int j = 0; j < 4; ++j){
      const int C = wc*64 + j*16 + fr;
      b[j] = *(const short8*)&sB[s][C*32 + ((fq ^ ((C>>1)&3))<<3)];
    }
    if (p + 2 < P) stg(p + 2);                 // overwrites slot read at p-1
    __builtin_amdgcn_s_setprio(1);
    #pragma unroll
    for (int i = 0; i < 4; ++i)
      #pragma unroll
      for (int j = 0; j < 4; ++j)
        acc[i][j] = __builtin_amdgcn_mfma_f32_16x16x32_bf16(a[i], b[j], acc[i][j], 0, 0, 0);
    __builtin_amdgcn_s_setprio(0);
    if (p + 1 < P){                            // guarantee slot p+1 landed
      if (p == P - 2) asm volatile("s_waitcnt vmcnt(0)" ::: "memory");
      else            asm volatile("s_waitcnt vmcnt(3)" ::: "memory");
      barx();
    }
  }

  #pragma unroll
  for (int mf = 0; mf < 4; ++mf){
    #pragma unroll
    for (int nf = 0; nf < 4; ++nf){
      #pragma unroll
      for (int rr = 0; rr < 4; ++rr){
        const int row = m0 + wr*64 + mf*16 + (fq<<2) + rr;
        const int col = n0 + wc*64 + nf*16 + fr;
        float v = acc[mf][nf][rr] + bias[col];
        if (pos)  v += pos[(size_t)(row % NP) * D_ + col];
        if (res)  v += res[(size_t)row * N + col];
        if (relu) v = fmaxf(v, 0.f);
        const size_t idx = (size_t)row * N + col;
        if (outf) outf[idx] = v;
        if (outb) outb[idx] = f2bf(v);
      }
    }
  }
}

// ---------------- gemm5p: BM=128 BN=128, 5-slot 32-k ring, 80KB LDS ----------
// 2 blocks/CU. TWO slots per barrier interval: iteration it reads slots
// 2it,2it+1 (12 ds_read), stages 2it+3,2it+4 (4 gld16), 16 MFMA, vmcnt(2), bar.
// Ring audit: phys (mod 5) of {2it,2it+1,2it+3,2it+4} distinct; stage targets
// were read >=1 barrier ago; end vmcnt(2) completes exactly next-iter's slots.
// Requires K%64==0 (P even), P>=6.
__global__ __launch_bounds__(512, 4) void gemm5p(
    const unsigned short* __restrict__ A,
    const unsigned short* __restrict__ W,
    const float* __restrict__ bias,
    const float* __restrict__ pos,
    const float* res,
    float* outf,
    unsigned short* outb,
    int M, int N, int K, int relu)
{
  __shared__ unsigned short sA[5][128*32];   // 40 KB
  __shared__ unsigned short sB[5][128*32];   // 40 KB
  const int NB = N >> 7;
  const int nwg = (int)gridDim.x;
  const int wid0 = (int)blockIdx.x;
  const int xcd = wid0 & 7, bidx = wid0 >> 3;
  const int q = nwg >> 3, r = nwg & 7;
  const int wid = (xcd < r ? xcd*(q+1) : r*(q+1) + (xcd-r)*q) + bidx;
  const int mb = wid / NB, nb = wid % NB;
  const int m0 = mb << 7, n0 = nb << 7;
  const int t = threadIdx.x;
  const int w = t >> 6, l = t & 63;
  const int wr = w >> 1, wc = w & 1;          // 4M x 2N
  const int fr = l & 15, fq = l >> 4;

  const int srow = l >> 2;
  const int schk = (l & 3) ^ ((l >> 3) & 3);

  const f32x4 zero = {0.f, 0.f, 0.f, 0.f};
  f32x4 acc[2][4];
  #pragma unroll
  for (int i = 0; i < 2; ++i)
    #pragma unroll
    for (int j = 0; j < 4; ++j) acc[i][j] = zero;

  const int P = K >> 5;                        // even, >= 6

  auto stg = [&](int h){
    const int s = h % 5;
    const int rb = w*16;
    gld16(A + (size_t)(m0 + rb + srow) * K + (h<<5) + (schk<<3), &sA[s][rb*32]);
    gld16(W + (size_t)(n0 + rb + srow) * K + (h<<5) + (schk<<3), &sB[s][rb*32]);
  };

  stg(0); stg(1); stg(2);
  asm volatile("s_waitcnt vmcnt(2)" ::: "memory");   // slots 0,1 landed
  barx();

  const int IT = P >> 1;
  for (int it = 0; it < IT; ++it){
    const int h0 = 2*it;
    const int s0 = h0 % 5, s1 = (h0+1) % 5;
    short8 a0[2], b0[4], a1[2], b1[4];
    #pragma unroll
    for (int i = 0; i < 2; ++i){
      const int R = wr*32 + i*16 + fr;
      const int o = R*32 + ((fq ^ ((R>>1)&3))<<3);
      a0[i] = *(const short8*)&sA[s0][o];
      a1[i] = *(const short8*)&sA[s1][o];
    }
    #pragma unroll
    for (int j = 0; j < 4; ++j){
      const int C = wc*64 + j*16 + fr;
      const int o = C*32 + ((fq ^ ((C>>1)&3))<<3);
      b0[j] = *(const short8*)&sB[s0][o];
      b1[j] = *(const short8*)&sB[s1][o];
    }
    const bool g3 = (h0 + 3) < P, g4 = (h0 + 4) < P;
    if (g3) stg(h0 + 3);
    if (g4) stg(h0 + 4);
    __builtin_amdgcn_s_setprio(1);
    #pragma unroll
    for (int i = 0; i < 2; ++i)
      #pragma unroll
      for (int j = 0; j < 4; ++j)
        acc[i][j] = __builtin_amdgcn_mfma_f32_16x16x32_bf16(a0[i], b0[j], acc[i][j], 0, 0, 0);
    #pragma unroll
    for (int i = 0; i < 2; ++i)
      #pragma unroll
      for (int j = 0; j < 4; ++j)
        acc[i][j] = __builtin_amdgcn_mfma_f32_16x16x32_bf16(a1[i], b1[j], acc[i][j], 0, 0, 0);
    __builtin_amdgcn_s_setprio(0);
    if (it + 1 < IT){
      if (g4) asm volatile("s_waitcnt vmcnt(2)" ::: "memory");
      else    asm volatile("s_waitcnt vmcnt(0)" ::: "memory");
      barx();
    }
  }

  #pragma unroll
  for (int mf = 0; mf < 2; ++mf){
    #pragma unroll
    for (int nf = 0; nf < 4; ++nf){
      #pragma unroll
      for (int rr = 0; rr < 4; ++rr){
        const int row = m0 + wr*32 + mf*16 + (fq<<2) + rr;
        const int col = n0 + wc*64 + nf*16 + fr;
        float v = acc[mf][nf][rr] + bias[col];
        if (pos)  v += pos[(size_t)(row % NP) * D_ + col];
        if (res)  v += res[(size_t)row * N + col];
        if (relu) v = fmaxf(v, 0.f);
        const size_t idx = (size_t)row * N + col;
        if (outf) outf[idx] = v;
        if (outb) outb[idx] = f2bf(v);
      }
    }
  }
}

// ---------------- fused attention v2 (round-5 version, verified) -------------
__global__ __launch_bounds__(384) void k_attn(const unsigned short* __restrict__ qkv,
                                              unsigned short* __restrict__ o)
{
  __shared__ unsigned short Kl[2][32*64];
  __shared__ unsigned short Vt[2][64*64];
  const int nwg = (int)gridDim.x;           // 576
  int wid = (int)blockIdx.x;
  wid = (wid & 7) * (nwg >> 3) + (wid >> 3);
  const int bh = wid / 3, qs = wid % 3;
  const int b = bh / HH, h = bh % HH;
  const unsigned short* base = qkv + (size_t)b * NP * 2304 + h * DHEAD;
  const int t = threadIdx.x;
  const int w = t >> 6, l = t & 63;
  const int fr = l & 15, fq = l >> 4;
  const int sg = l & 7;
  const int sr = ((w & 3) << 3) + (l >> 3);
  const bool stw = (t < 256);

  short8 qfa[2], qfb[2];
  #pragma unroll
  for (int qt = 0; qt < 2; ++qt){
    const size_t qrow = (size_t)(qs*192 + (qt*6 + w)*16 + fr);
    qfa[qt] = *(const short8*)(base + qrow*2304 + (fq<<3));
    qfb[qt] = *(const short8*)(base + qrow*2304 + 32 + (fq<<3));
  }

  const f32x4 zero = {0.f, 0.f, 0.f, 0.f};
  float mx_[2] = {-1e30f, -1e30f};
  float ls_[2] = {0.f, 0.f};
  f32x4 oa[2][4];
  #pragma unroll
  for (int qt = 0; qt < 2; ++qt)
    #pragma unroll
    for (int nf = 0; nf < 4; ++nf) oa[qt][nf] = zero;

  if (stw){
    gld16(base + 768 + (size_t)sr*2304 + ((sg ^ (sr&7))<<3), &Kl[0][(w&3)*512]);
    short8 vv = *(const short8*)(base + 1536 + (size_t)sr*2304 + (sg<<3));
    asm volatile("s_waitcnt vmcnt(0)" ::: "memory");
    #pragma unroll
    for (int j = 0; j < 8; ++j){
      const int d = sg*8 + j;
      const int off = (d<<7) + ((((sr>>3) ^ j ^ sg) & 7) << 4) + ((sr&7)<<1);
      *(unsigned short*)((char*)&Vt[0][0] + off) = ((const unsigned short*)&vv)[j];
    }
  }
  __syncthreads();

  for (int kt = 0; kt < 18; ++kt){
    const int buf = kt & 1;
    short8 vv;
    const bool st = stw && (kt < 17);
    if (st){
      const int key = (kt+1)*32 + sr;
      gld16(base + 768 + (size_t)key*2304 + ((sg ^ (sr&7))<<3), &Kl[buf^1][(w&3)*512]);
      vv = *(const short8*)(base + 1536 + (size_t)key*2304 + (sg<<3));
    }

    const char* kb = (const char*)&Kl[buf][0];
    const int r0 = fr, r1 = 16 + fr;
    const short8 k00 = *(const short8*)(kb + (r0<<7) + (((fq    ) ^ (r0&7))<<4));
    const short8 k01 = *(const short8*)(kb + (r0<<7) + (((4+fq ) ^ (r0&7))<<4));
    const short8 k10 = *(const short8*)(kb + (r1<<7) + (((fq    ) ^ (r1&7))<<4));
    const short8 k11 = *(const short8*)(kb + (r1<<7) + (((4+fq ) ^ (r1&7))<<4));
    const char* vb = (const char*)&Vt[buf][0];

    #pragma unroll
    for (int qt = 0; qt < 2; ++qt){
      f32x4 s0 = zero, s1 = zero;
      s0 = __builtin_amdgcn_mfma_f32_16x16x32_bf16(k00, qfa[qt], s0, 0, 0, 0);
      s0 = __builtin_amdgcn_mfma_f32_16x16x32_bf16(k01, qfb[qt], s0, 0, 0, 0);
      s1 = __builtin_amdgcn_mfma_f32_16x16x32_bf16(k10, qfa[qt], s1, 0, 0, 0);
      s1 = __builtin_amdgcn_mfma_f32_16x16x32_bf16(k11, qfb[qt], s1, 0, 0, 0);
      float mx = fmaxf(fmaxf(fmaxf(s0[0], s0[1]), fmaxf(s0[2], s0[3])),
                       fmaxf(fmaxf(s1[0], s1[1]), fmaxf(s1[2], s1[3])));
      mx = fmaxf(mx, __shfl_xor(mx, 16));
      mx = fmaxf(mx, __shfl_xor(mx, 32));
      const float mn = fmaxf(mx_[qt], mx * SCL);
      const float fc = exp2f(mx_[qt] - mn);
      const float p0 = exp2f(s0[0]*SCL - mn), p1 = exp2f(s0[1]*SCL - mn);
      const float p2 = exp2f(s0[2]*SCL - mn), p3 = exp2f(s0[3]*SCL - mn);
      const float p4 = exp2f(s1[0]*SCL - mn), p5 = exp2f(s1[1]*SCL - mn);
      const float p6 = exp2f(s1[2]*SCL - mn), p7 = exp2f(s1[3]*SCL - mn);
      float ps = ((p0+p1)+(p2+p3)) + ((p4+p5)+(p6+p7));
      ps += __shfl_xor(ps, 16);
      ps += __shfl_xor(ps, 32);
      ls_[qt] = ls_[qt] * fc + ps;
      mx_[qt] = mn;
      if (!__all(fc == 1.0f)){
        const float fA = __shfl(fc, (fq<<2) + 0);
        const float fB = __shfl(fc, (fq<<2) + 1);
        const float fC = __shfl(fc, (fq<<2) + 2);
        const float fD = __shfl(fc, (fq<<2) + 3);
        #pragma unroll
        for (int nf = 0; nf < 4; ++nf){
          oa[qt][nf][0] *= fA; oa[qt][nf][1] *= fB;
          oa[qt][nf][2] *= fC; oa[qt][nf][3] *= fD;
        }
      }
      unsigned d0, d1, d2, d3;
      asm("v_cvt_pk_bf16_f32 %0, %1, %2" : "=v"(d0) : "v"(p0), "v"(p1));
      asm("v_cvt_pk_bf16_f32 %0, %1, %2" : "=v"(d1) : "v"(p2), "v"(p3));
      asm("v_cvt_pk_bf16_f32 %0, %1, %2" : "=v"(d2) : "v"(p4), "v"(p5));
      asm("v_cvt_pk_bf16_f32 %0, %1, %2" : "=v"(d3) : "v"(p6), "v"(p7));
      const int srcA = fr + ((fq & 1) << 5);
      const unsigned a0 = (unsigned)__shfl((int)d0, srcA);
      const unsigned a1 = (unsigned)__shfl((int)d1, srcA);
      const unsigned a2 = (unsigned)__shfl((int)d2, srcA);
      const unsigned a3 = (unsigned)__shfl((int)d3, srcA);
      const unsigned b0 = (unsigned)__shfl((int)d0, srcA + 16);
      const unsigned b1 = (unsigned)__shfl((int)d1, srcA + 16);
      const unsigned b2 = (unsigned)__shfl((int)d2, srcA + 16);
      const unsigned b3 = (unsigned)__shfl((int)d3, srcA + 16);
      const bool hi = fq >= 2;
      union { unsigned u[4]; short8 v; } pk;
      pk.u[0] = hi ? a2 : a0;
      pk.u[1] = hi ? a3 : a1;
      pk.u[2] = hi ? b2 : b0;
      pk.u[3] = hi ? b3 : b1;
      const short8 pa = pk.v;
      #pragma unroll
      for (int nf = 0; nf < 4; ++nf){
        const int d = (nf<<4) + fr;
        const short8 vf = *(const short8*)(vb + (d<<7) + (((fq ^ (d&7) ^ (d>>3)) & 7)<<4));
        oa[qt][nf] = __builtin_amdgcn_mfma_f32_16x16x32_bf16(pa, vf, oa[qt][nf], 0, 0, 0);
      }
    }

    if (st){
      asm volatile("s_waitcnt vmcnt(0)" ::: "memory");
      #pragma unroll
      for (int j = 0; j < 8; ++j){
        const int d = sg*8 + j;
        const int off = (d<<7) + ((((sr>>3) ^ j ^ sg) & 7) << 4) + ((sr&7)<<1);
        *(unsigned short*)((char*)&Vt[buf^1][0] + off) = ((const unsigned short*)&vv)[j];
      }
    }
    __syncthreads();
  }

  #pragma unroll
  for (int qt = 0; qt < 2; ++qt){
    const float rl = 1.f / ls_[qt];
    const float rA = __shfl(rl, (fq<<2)+0), rB = __shfl(rl, (fq<<2)+1);
    const float rC = __shfl(rl, (fq<<2)+2), rD = __shfl(rl, (fq<<2)+3);
    const size_t r0 = (size_t)(b*NP + qs*192 + (qt*6 + w)*16 + (fq<<2));
    #pragma unroll
    for (int nf = 0; nf < 4; ++nf){
      const int col = h*DHEAD + (nf<<4) + fr;
      o[(r0 + 0)*D_ + col] = f2bf(oa[qt][nf][0] * rA);
      o[(r0 + 1)*D_ + col] = f2bf(oa[qt][nf][1] * rB);
      o[(r0 + 2)*D_ + col] = f2bf(oa[qt][nf][2] * rC);
      o[(r0 + 3)*D_ + col] = f2bf(oa[qt][nf][3] * rD);
    }
  }
}

// ---------------- fused weight conversion (all 4 weight groups) --------------
__global__ void k_wconv(const float* __restrict__ Wq, const float* __restrict__ Wk,
                        const float* __restrict__ Wv, const float* __restrict__ Wo,
                        const float* __restrict__ W1, const float* __restrict__ W2,
                        unsigned short* __restrict__ wqkv, unsigned short* __restrict__ wo,
                        unsigned short* __restrict__ w1, unsigned short* __restrict__ w2){
  const long Q4 = 5308416, O4 = 1769472, F4 = 7077888;
  const long n4 = Q4 + O4 + F4 + F4;
  long i = (long)blockIdx.x * blockDim.x + threadIdx.x;
  const long st = (long)gridDim.x * blockDim.x;
  for (; i < n4; i += st){
    if (i < Q4){
      const int lay = (int)(i / (2304 * 192));
      const int rem = (int)(i % (2304 * 192));
      const int r = rem / 192, k4 = rem % 192;
      const float* s = (r < 768) ? Wq : ((r < 1536) ? Wk : Wv);
      const int rr = (r < 768) ? r : ((r < 1536) ? r - 768 : r - 1536);
      ((us4*)wqkv)[i] = f2bf4(*(const float4v*)(s + (size_t)lay * 589824 + (size_t)rr * 768 + k4*4));
    } else if (i < Q4 + O4){
      const long j = i - Q4;
      ((us4*)wo)[j] = f2bf4(((const float4v*)Wo)[j]);
    } else if (i < Q4 + O4 + F4){
      const long j = i - Q4 - O4;
      ((us4*)w1)[j] = f2bf4(((const float4v*)W1)[j]);
    } else {
      const long j = i - Q4 - O4 - F4;
      ((us4*)w2)[j] = f2bf4(((const float4v*)W2)[j]);
    }
  }
}

__global__ void k_pack_qkvb(const float* __restrict__ bq, const float* __restrict__ bk,
                            const float* __restrict__ bv, float* __restrict__ dst){
  const int i = blockIdx.x * 256 + threadIdx.x;
  if (i >= 12 * 2304) return;
  const int lay = i / 2304, r = i % 2304;
  const float* s = (r < 768) ? bq : ((r < 1536) ? bk : bv);
  const int rr = (r < 768) ? r : ((r < 1536) ? r - 768 : r - 1536);
  dst[i] = s[lay * 768 + rr];
}

__global__ void k_patchw(const float* __restrict__ s, unsigned short* __restrict__ d){
  const long n4 = (long)768 * (KPAT/4);
  long i = (long)blockIdx.x * blockDim.x + threadIdx.x;
  const long st = (long)gridDim.x * blockDim.x;
  for (; i < n4; i += st){
    const int r = (int)(i / (KPAT/4)), k4 = (int)(i % (KPAT/4));
    us4 o = {0,0,0,0};
    if (k4*4 < 1200)
      o = f2bf4(*(const float4v*)(s + (size_t)r * 1200 + k4*4));
    ((us4*)d)[i] = o;
  }
}

__global__ void k_patches(const float* __restrict__ x, unsigned short* __restrict__ d){
  const long n4 = (long)MROWS * (KPAT/4);
  long i = (long)blockIdx.x * blockDim.x + threadIdx.x;
  const long st = (long)gridDim.x * blockDim.x;
  for (; i < n4; i += st){
    const int mrow = (int)(i / (KPAT/4)), k4 = (int)(i % (KPAT/4));
    const int k = k4 * 4;
    us4 o = {0,0,0,0};
    if (k < 1200){
      const int c = k / 400, rem = k % 400, py = rem / 20, px = rem % 20;
      const int b = mrow / NP, pn = mrow % NP, hp = pn / 18, wp = pn % 18;
      const float4v v = *(const float4v*)(x + ((((size_t)b * 3 + c) * 640 + hp * 20 + py) * 360 + wp * 20 + px));
      o = f2bf4(v);
    }
    ((us4*)d)[i] = o;
  }
}

__global__ __launch_bounds__(256) void k_ln(float* h, unsigned short* hb,
                                            const float* __restrict__ g,
                                            const float* __restrict__ bt){
  const int r = blockIdx.x, t = threadIdx.x;
  const size_t base = (size_t)r * D_;
  const float x0 = h[base + t], x1 = h[base + t + 256], x2 = h[base + t + 512];
  float s = x0 + x1 + x2;
  #pragma unroll
  for (int o = 1; o < 64; o <<= 1) s += __shfl_xor(s, o);
  __shared__ float red[8];
  const int w = t >> 6, l = t & 63;
  if (l == 0) red[w] = s;
  __syncthreads();
  const float mu = (red[0] + red[1] + red[2] + red[3]) * (1.f / 768.f);
  const float d0 = x0 - mu, d1 = x1 - mu, d2 = x2 - mu;
  float v = d0*d0 + d1*d1 + d2*d2;
  #pragma unroll
  for (int o = 1; o < 64; o <<= 1) v += __shfl_xor(v, o);
  if (l == 0) red[4 + w] = v;
  __syncthreads();
  const float var = (red[4] + red[5] + red[6] + red[7]) * (1.f / 768.f);
  const float rs = rsqrtf(var + 1e-5f);
  const float y0 = d0 * rs * g[t]       + bt[t];
  const float y1 = d1 * rs * g[t + 256] + bt[t + 256];
  const float y2 = d2 * rs * g[t + 512] + bt[t + 512];
  h[base + t] = y0; h[base + t + 256] = y1; h[base + t + 512] = y2;
  hb[base + t] = f2bf(y0); hb[base + t + 256] = f2bf(y1); hb[base + t + 512] = f2bf(y2);
}

__global__ void k_pool(const float* __restrict__ h, float* __restrict__ p){
  const int i = blockIdx.x * 256 + threadIdx.x;   // 12288
  const int b = i / D_, c = i % D_;
  const float* base = h + (size_t)b * NP * D_ + c;
  float s = 0.f;
  for (int n = 0; n < NP; ++n) s += base[(size_t)n * D_];
  p[i] = s * (1.f / 576.f);
}

__global__ __launch_bounds__(64) void k_fc(const float* __restrict__ p, const float* __restrict__ w,
                                           const float* __restrict__ bias, float* __restrict__ out){
  const int oi = blockIdx.x;                       // 160
  const int b = oi / 10, j = oi % 10;
  const int l = threadIdx.x;
  float s = 0.f;
  for (int c = l; c < D_; c += 64) s += p[b * D_ + c] * w[j * D_ + c];
  #pragma unroll
  for (int o = 1; o < 64; o <<= 1) s += __shfl_xor(s, o);
  if (l == 0) out[oi] = s + bias[j];
}

// ---------------- launch ------------------------------------------------------
extern "C" void kernel_launch(void* const* d_in, const int* in_sizes, int n_in,
                              void* d_out, int out_size, void* d_ws, size_t ws_size,
                              hipStream_t stream)
{
  const float* x       = (const float*)d_in[0];
  const float* patch_w = (const float*)d_in[1];
  const float* patch_b = (const float*)d_in[2];
  const float* pos_emb = (const float*)d_in[3];
  const float* ln_g    = (const float*)d_in[4];
  const float* ln_b    = (const float*)d_in[5];
  const float* Wq      = (const float*)d_in[6];
  const float* bq      = (const float*)d_in[7];
  const float* Wk      = (const float*)d_in[8];
  const float* bk      = (const float*)d_in[9];
  const float* Wv      = (const float*)d_in[10];
  const float* bv      = (const float*)d_in[11];
  const float* Wo      = (const float*)d_in[12];
  const float* bo      = (const float*)d_in[13];
  const float* W1      = (const float*)d_in[14];
  const float* b1      = (const float*)d_in[15];
  const float* W2      = (const float*)d_in[16];
  const float* b2      = (const float*)d_in[17];
  const float* fc_w    = (const float*)d_in[18];
  const float* fc_b    = (const float*)d_in[19];
  float* out = (float*)d_out;
  (void)in_sizes; (void)n_in; (void)out_size; (void)ws_size;

  char* ws = (char*)d_ws;
  size_t off = 0;
  auto alloc = [&](size_t bytes) -> char* {
    char* p = ws + off;
    off += (bytes + 255) & ~(size_t)255;
    return p;
  };
  unsigned short* wqkv    = (unsigned short*)alloc((size_t)12*2304*768*2);
  unsigned short* wo      = (unsigned short*)alloc((size_t)12*768*768*2);
  unsigned short* w1      = (unsigned short*)alloc((size_t)12*3072*768*2);
  unsigned short* w2      = (unsigned short*)alloc((size_t)12*768*3072*2);
  unsigned short* wp      = (unsigned short*)alloc((size_t)768*KPAT*2);
  float*          bqkv    = (float*)alloc((size_t)12*2304*4);
  unsigned short* patches = (unsigned short*)alloc((size_t)MROWS*KPAT*2);
  float*          hf      = (float*)alloc((size_t)MROWS*D_*4);
  unsigned short* hb      = (unsigned short*)alloc((size_t)MROWS*D_*2);
  unsigned short* qkvb    = (unsigned short*)alloc((size_t)MROWS*2304*2);
  unsigned short* ob      = (unsigned short*)alloc((size_t)MROWS*D_*2);
  unsigned short* ffb     = (unsigned short*)alloc((size_t)MROWS*3072*2);
  float*          pooled  = (float*)alloc((size_t)16*D_*4);

  // weight conversion / packing (bf16), fused + vectorized x4
  k_wconv<<<8192, 256, 0, stream>>>(Wq, Wk, Wv, Wo, W1, W2, wqkv, wo, w1, w2);
  k_pack_qkvb<<<(12*2304 + 255)/256, 256, 0, stream>>>(bq, bk, bv, bqkv);
  k_patchw<<<2048, 256, 0, stream>>>(patch_w, wp);
  k_patches<<<2048, 256, 0, stream>>>(x, patches);

  // patch embed (+bias +pos) -> hf ; LN -> hf (in-place) + hb
  gemm5p<<<72*6, 512, 0, stream>>>(patches, wp, patch_b, pos_emb,
                                   nullptr, hf, nullptr, MROWS, 768, KPAT, 0);
  k_ln<<<MROWS, 256, 0, stream>>>(hf, hb, ln_g, ln_b);

  for (int l = 0; l < 12; ++l){
    gemm3r<<<36*18, 512, 0, stream>>>(hb, wqkv + (size_t)l*2304*768, bqkv + l*2304,
                                      nullptr, nullptr, nullptr, qkvb, MROWS, 2304, 768, 0);
    k_attn<<<576, 384, 0, stream>>>(qkvb, ob);
    gemm5p<<<72*6, 512, 0, stream>>>(ob, wo + (size_t)l*768*768, bo + l*768,
                                     nullptr, hf, hf, hb, MROWS, 768, 768, 0);
    gemm3r<<<36*24, 512, 0, stream>>>(hb, w1 + (size_t)l*3072*768, b1 + (size_t)l*3072,
                                      nullptr, nullptr, nullptr, ffb, MROWS, 3072, 768, 1);
    gemm5p<<<72*6, 512, 0, stream>>>(ffb, w2 + (size_t)l*768*3072, b2 + l*768,
                                     nullptr, hf, hf, hb, MROWS, 768, 3072, 0);
  }
  k_pool<<<48, 256, 0, stream>>>(hf, pooled);
  k_fc<<<160, 64, 0, stream>>>(pooled, fc_w, fc_b, out);
}

// Round 15
// 3501.824 us; speedup vs baseline: 1.0211x; 1.0211x over previous
//
#include <hip/hip_runtime.h>
#include <stdint.h>
#include <stddef.h>

typedef __attribute__((ext_vector_type(8))) short short8;
typedef __attribute__((ext_vector_type(4))) float f32x4;
typedef __attribute__((ext_vector_type(4))) float float4v;
typedef __attribute__((ext_vector_type(4))) unsigned short us4;
typedef __attribute__((ext_vector_type(8))) unsigned short us8;

#define D_    768
#define HH    12
#define DHEAD 64
#define NP    576
#define BB    16
#define MROWS 9216      // BB*NP
#define KPAT  1216      // 1200 padded to multiple of 64
#define SCL   0.18033688011112042f   // 0.125 * log2(e)

static __device__ __forceinline__ unsigned short f2bf(float f){
  union { float f; unsigned int u; } v; v.f = f;
  unsigned int u = v.u;
  return (unsigned short)((u + 0x7FFFu + ((u >> 16) & 1u)) >> 16);
}

static __device__ __forceinline__ us4 f2bf4(float4v v){
  us4 r;
  r.x = f2bf(v.x); r.y = f2bf(v.y); r.z = f2bf(v.z); r.w = f2bf(v.w);
  return r;
}

static __device__ __forceinline__ void gld16(const void* g, void* l){
  __builtin_amdgcn_global_load_lds((const __attribute__((address_space(1))) void*)g,
                                   (__attribute__((address_space(3))) void*)l,
                                   16, 0, 0);
}

static __device__ __forceinline__ void barx(){
  asm volatile("" ::: "memory");
  __builtin_amdgcn_s_barrier();
  asm volatile("" ::: "memory");
}

// ---------------- gemm3r: BM=256 BN=128, 3-slot 32-k ring, 73.7KB LDS --------
// 2 blocks/CU. 8 waves 4Mx2N, 16 MFMA/phase, ONE barrier per phase.
__global__ __launch_bounds__(512, 4) void gemm3r(
    const unsigned short* __restrict__ A,
    const unsigned short* __restrict__ W,
    const float* __restrict__ bias,
    const float* __restrict__ pos,
    const float* res,
    float* outf,
    unsigned short* outb,
    int M, int N, int K, int relu)
{
  __shared__ unsigned short sA[3][256*32];   // 48 KB
  __shared__ unsigned short sB[3][128*32];   // 24 KB
  const int NB = N >> 7;
  const int nwg = (int)gridDim.x;
  const int wid0 = (int)blockIdx.x;
  const int xcd = wid0 & 7, bidx = wid0 >> 3;
  const int q = nwg >> 3, r = nwg & 7;
  const int wid = (xcd < r ? xcd*(q+1) : r*(q+1) + (xcd-r)*q) + bidx;
  const int mb = wid / NB, nb = wid % NB;
  const int m0 = mb << 8, n0 = nb << 7;
  const int t = threadIdx.x;
  const int w = t >> 6, l = t & 63;
  const int wr = w >> 1, wc = w & 1;          // 4M x 2N wave grid
  const int fr = l & 15, fq = l >> 4;
  const int srow = l >> 2;
  const int schk = (l & 3) ^ ((l >> 3) & 3);

  const f32x4 zero = {0.f, 0.f, 0.f, 0.f};
  f32x4 acc[4][4];
  #pragma unroll
  for (int i = 0; i < 4; ++i)
    #pragma unroll
    for (int j = 0; j < 4; ++j) acc[i][j] = zero;

  const int P = K >> 5;                        // >= 3

  auto stg = [&](int h){
    const int s = h % 3;
    #pragma unroll
    for (int i = 0; i < 2; ++i){
      const int rb = i*128 + w*16;
      gld16(A + (size_t)(m0 + rb + srow) * K + (h<<5) + (schk<<3), &sA[s][rb*32]);
    }
    const int rb = w*16;
    gld16(W + (size_t)(n0 + rb + srow) * K + (h<<5) + (schk<<3), &sB[s][rb*32]);
  };

  stg(0); stg(1);
  asm volatile("s_waitcnt vmcnt(3)" ::: "memory");   // slot 0 landed
  barx();

  for (int p = 0; p < P; ++p){
    const int s = p % 3;
    short8 a[4], b[4];
    #pragma unroll
    for (int i = 0; i < 4; ++i){
      const int R = wr*64 + i*16 + fr;
      a[i] = *(const short8*)&sA[s][R*32 + ((fq ^ ((R>>1)&3))<<3)];
    }
    #pragma unroll
    for (int j = 0; j < 4; ++j){
      const int C = wc*64 + j*16 + fr;
      b[j] = *(const short8*)&sB[s][C*32 + ((fq ^ ((C>>1)&3))<<3)];
    }
    if (p + 2 < P) stg(p + 2);                 // overwrites slot read at p-1
    __builtin_amdgcn_s_setprio(1);
    #pragma unroll
    for (int i = 0; i < 4; ++i)
      #pragma unroll
      for (int j = 0; j < 4; ++j)
        acc[i][j] = __builtin_amdgcn_mfma_f32_16x16x32_bf16(a[i], b[j], acc[i][j], 0, 0, 0);
    __builtin_amdgcn_s_setprio(0);
    if (p + 1 < P){                            // guarantee slot p+1 landed
      if (p == P - 2) asm volatile("s_waitcnt vmcnt(0)" ::: "memory");
      else            asm volatile("s_waitcnt vmcnt(3)" ::: "memory");
      barx();
    }
  }

  #pragma unroll
  for (int mf = 0; mf < 4; ++mf){
    #pragma unroll
    for (int nf = 0; nf < 4; ++nf){
      #pragma unroll
      for (int rr = 0; rr < 4; ++rr){
        const int row = m0 + wr*64 + mf*16 + (fq<<2) + rr;
        const int col = n0 + wc*64 + nf*16 + fr;
        float v = acc[mf][nf][rr] + bias[col];
        if (pos)  v += pos[(size_t)(row % NP) * D_ + col];
        if (res)  v += res[(size_t)row * N + col];
        if (relu) v = fmaxf(v, 0.f);
        const size_t idx = (size_t)row * N + col;
        if (outf) outf[idx] = v;
        if (outb) outb[idx] = f2bf(v);
      }
    }
  }
}

// ---------------- gemm34: BM=128 BN=128, 3-slot 32-k ring, 48KB LDS ----------
// 3 blocks/CU (24 waves) — max TLP for the latency-bound phases. 8 waves
// 4Mx2N, 8 MFMA/phase, ONE barrier per phase; steady vmcnt(2) (2 gld16/slot).
__global__ __launch_bounds__(512, 4) void gemm34(
    const unsigned short* __restrict__ A,
    const unsigned short* __restrict__ W,
    const float* __restrict__ bias,
    const float* __restrict__ pos,
    const float* res,
    float* outf,
    unsigned short* outb,
    int M, int N, int K, int relu)
{
  __shared__ unsigned short sA[3][128*32];   // 24 KB
  __shared__ unsigned short sB[3][128*32];   // 24 KB
  const int NB = N >> 7;
  const int nwg = (int)gridDim.x;
  const int wid0 = (int)blockIdx.x;
  const int xcd = wid0 & 7, bidx = wid0 >> 3;
  const int q = nwg >> 3, r = nwg & 7;
  const int wid = (xcd < r ? xcd*(q+1) : r*(q+1) + (xcd-r)*q) + bidx;
  const int mb = wid / NB, nb = wid % NB;
  const int m0 = mb << 7, n0 = nb << 7;
  const int t = threadIdx.x;
  const int w = t >> 6, l = t & 63;
  const int wr = w >> 1, wc = w & 1;          // 4M x 2N
  const int fr = l & 15, fq = l >> 4;

  const int srow = l >> 2;
  const int schk = (l & 3) ^ ((l >> 3) & 3);

  const f32x4 zero = {0.f, 0.f, 0.f, 0.f};
  f32x4 acc[2][4];
  #pragma unroll
  for (int i = 0; i < 2; ++i)
    #pragma unroll
    for (int j = 0; j < 4; ++j) acc[i][j] = zero;

  const int P = K >> 5;                        // >= 3

  auto stg = [&](int h){
    const int s = h % 3;
    const int rb = w*16;
    gld16(A + (size_t)(m0 + rb + srow) * K + (h<<5) + (schk<<3), &sA[s][rb*32]);
    gld16(W + (size_t)(n0 + rb + srow) * K + (h<<5) + (schk<<3), &sB[s][rb*32]);
  };

  stg(0); stg(1);
  asm volatile("s_waitcnt vmcnt(2)" ::: "memory");   // slot 0 landed
  barx();

  short8 a[2], b[4];
  for (int p = 0; p < P; ++p){
    const int s = p % 3;
    #pragma unroll
    for (int i = 0; i < 2; ++i){
      const int R = wr*32 + i*16 + fr;
      a[i] = *(const short8*)&sA[s][R*32 + ((fq ^ ((R>>1)&3))<<3)];
    }
    #pragma unroll
    for (int i = 0; i < 4; ++i){
      const int C = wc*64 + i*16 + fr;
      b[i] = *(const short8*)&sB[s][C*32 + ((fq ^ ((C>>1)&3))<<3)];
    }
    if (p + 2 < P) stg(p + 2);                 // overwrites slot read at p-1
    __builtin_amdgcn_s_setprio(1);
    #pragma unroll
    for (int i = 0; i < 2; ++i)
      #pragma unroll
      for (int j = 0; j < 4; ++j)
        acc[i][j] = __builtin_amdgcn_mfma_f32_16x16x32_bf16(a[i], b[j], acc[i][j], 0, 0, 0);
    __builtin_amdgcn_s_setprio(0);
    if (p + 1 < P){                            // ensure slot p+1 landed
      if (p == P - 2) asm volatile("s_waitcnt vmcnt(0)" ::: "memory");
      else            asm volatile("s_waitcnt vmcnt(2)" ::: "memory");
      barx();
    }
  }

  #pragma unroll
  for (int mf = 0; mf < 2; ++mf){
    #pragma unroll
    for (int nf = 0; nf < 4; ++nf){
      #pragma unroll
      for (int rr = 0; rr < 4; ++rr){
        const int row = m0 + wr*32 + mf*16 + (fq<<2) + rr;
        const int col = n0 + wc*64 + nf*16 + fr;
        float v = acc[mf][nf][rr] + bias[col];
        if (pos)  v += pos[(size_t)(row % NP) * D_ + col];
        if (res)  v += res[(size_t)row * N + col];
        if (relu) v = fmaxf(v, 0.f);
        const size_t idx = (size_t)row * N + col;
        if (outf) outf[idx] = v;
        if (outb) outb[idx] = f2bf(v);
      }
    }
  }
}

// ---------------- fused attention v2 (round-5 version, verified) -------------
__global__ __launch_bounds__(384) void k_attn(const unsigned short* __restrict__ qkv,
                                              unsigned short* __restrict__ o)
{
  __shared__ unsigned short Kl[2][32*64];
  __shared__ unsigned short Vt[2][64*64];
  const int nwg = (int)gridDim.x;           // 576
  int wid = (int)blockIdx.x;
  wid = (wid & 7) * (nwg >> 3) + (wid >> 3);
  const int bh = wid / 3, qs = wid % 3;
  const int b = bh / HH, h = bh % HH;
  const unsigned short* base = qkv + (size_t)b * NP * 2304 + h * DHEAD;
  const int t = threadIdx.x;
  const int w = t >> 6, l = t & 63;
  const int fr = l & 15, fq = l >> 4;
  const int sg = l & 7;
  const int sr = ((w & 3) << 3) + (l >> 3);
  const bool stw = (t < 256);

  short8 qfa[2], qfb[2];
  #pragma unroll
  for (int qt = 0; qt < 2; ++qt){
    const size_t qrow = (size_t)(qs*192 + (qt*6 + w)*16 + fr);
    qfa[qt] = *(const short8*)(base + qrow*2304 + (fq<<3));
    qfb[qt] = *(const short8*)(base + qrow*2304 + 32 + (fq<<3));
  }

  const f32x4 zero = {0.f, 0.f, 0.f, 0.f};
  float mx_[2] = {-1e30f, -1e30f};
  float ls_[2] = {0.f, 0.f};
  f32x4 oa[2][4];
  #pragma unroll
  for (int qt = 0; qt < 2; ++qt)
    #pragma unroll
    for (int nf = 0; nf < 4; ++nf) oa[qt][nf] = zero;

  if (stw){
    gld16(base + 768 + (size_t)sr*2304 + ((sg ^ (sr&7))<<3), &Kl[0][(w&3)*512]);
    short8 vv = *(const short8*)(base + 1536 + (size_t)sr*2304 + (sg<<3));
    asm volatile("s_waitcnt vmcnt(0)" ::: "memory");
    #pragma unroll
    for (int j = 0; j < 8; ++j){
      const int d = sg*8 + j;
      const int off = (d<<7) + ((((sr>>3) ^ j ^ sg) & 7) << 4) + ((sr&7)<<1);
      *(unsigned short*)((char*)&Vt[0][0] + off) = ((const unsigned short*)&vv)[j];
    }
  }
  __syncthreads();

  for (int kt = 0; kt < 18; ++kt){
    const int buf = kt & 1;
    short8 vv;
    const bool st = stw && (kt < 17);
    if (st){
      const int key = (kt+1)*32 + sr;
      gld16(base + 768 + (size_t)key*2304 + ((sg ^ (sr&7))<<3), &Kl[buf^1][(w&3)*512]);
      vv = *(const short8*)(base + 1536 + (size_t)key*2304 + (sg<<3));
    }

    const char* kb = (const char*)&Kl[buf][0];
    const int r0 = fr, r1 = 16 + fr;
    const short8 k00 = *(const short8*)(kb + (r0<<7) + (((fq    ) ^ (r0&7))<<4));
    const short8 k01 = *(const short8*)(kb + (r0<<7) + (((4+fq ) ^ (r0&7))<<4));
    const short8 k10 = *(const short8*)(kb + (r1<<7) + (((fq    ) ^ (r1&7))<<4));
    const short8 k11 = *(const short8*)(kb + (r1<<7) + (((4+fq ) ^ (r1&7))<<4));
    const char* vb = (const char*)&Vt[buf][0];

    #pragma unroll
    for (int qt = 0; qt < 2; ++qt){
      f32x4 s0 = zero, s1 = zero;
      s0 = __builtin_amdgcn_mfma_f32_16x16x32_bf16(k00, qfa[qt], s0, 0, 0, 0);
      s0 = __builtin_amdgcn_mfma_f32_16x16x32_bf16(k01, qfb[qt], s0, 0, 0, 0);
      s1 = __builtin_amdgcn_mfma_f32_16x16x32_bf16(k10, qfa[qt], s1, 0, 0, 0);
      s1 = __builtin_amdgcn_mfma_f32_16x16x32_bf16(k11, qfb[qt], s1, 0, 0, 0);
      float mx = fmaxf(fmaxf(fmaxf(s0[0], s0[1]), fmaxf(s0[2], s0[3])),
                       fmaxf(fmaxf(s1[0], s1[1]), fmaxf(s1[2], s1[3])));
      mx = fmaxf(mx, __shfl_xor(mx, 16));
      mx = fmaxf(mx, __shfl_xor(mx, 32));
      const float mn = fmaxf(mx_[qt], mx * SCL);
      const float fc = exp2f(mx_[qt] - mn);
      const float p0 = exp2f(s0[0]*SCL - mn), p1 = exp2f(s0[1]*SCL - mn);
      const float p2 = exp2f(s0[2]*SCL - mn), p3 = exp2f(s0[3]*SCL - mn);
      const float p4 = exp2f(s1[0]*SCL - mn), p5 = exp2f(s1[1]*SCL - mn);
      const float p6 = exp2f(s1[2]*SCL - mn), p7 = exp2f(s1[3]*SCL - mn);
      float ps = ((p0+p1)+(p2+p3)) + ((p4+p5)+(p6+p7));
      ps += __shfl_xor(ps, 16);
      ps += __shfl_xor(ps, 32);
      ls_[qt] = ls_[qt] * fc + ps;
      mx_[qt] = mn;
      if (!__all(fc == 1.0f)){
        const float fA = __shfl(fc, (fq<<2) + 0);
        const float fB = __shfl(fc, (fq<<2) + 1);
        const float fC = __shfl(fc, (fq<<2) + 2);
        const float fD = __shfl(fc, (fq<<2) + 3);
        #pragma unroll
        for (int nf = 0; nf < 4; ++nf){
          oa[qt][nf][0] *= fA; oa[qt][nf][1] *= fB;
          oa[qt][nf][2] *= fC; oa[qt][nf][3] *= fD;
        }
      }
      unsigned d0, d1, d2, d3;
      asm("v_cvt_pk_bf16_f32 %0, %1, %2" : "=v"(d0) : "v"(p0), "v"(p1));
      asm("v_cvt_pk_bf16_f32 %0, %1, %2" : "=v"(d1) : "v"(p2), "v"(p3));
      asm("v_cvt_pk_bf16_f32 %0, %1, %2" : "=v"(d2) : "v"(p4), "v"(p5));
      asm("v_cvt_pk_bf16_f32 %0, %1, %2" : "=v"(d3) : "v"(p6), "v"(p7));
      const int srcA = fr + ((fq & 1) << 5);
      const unsigned a0 = (unsigned)__shfl((int)d0, srcA);
      const unsigned a1 = (unsigned)__shfl((int)d1, srcA);
      const unsigned a2 = (unsigned)__shfl((int)d2, srcA);
      const unsigned a3 = (unsigned)__shfl((int)d3, srcA);
      const unsigned b0 = (unsigned)__shfl((int)d0, srcA + 16);
      const unsigned b1 = (unsigned)__shfl((int)d1, srcA + 16);
      const unsigned b2 = (unsigned)__shfl((int)d2, srcA + 16);
      const unsigned b3 = (unsigned)__shfl((int)d3, srcA + 16);
      const bool hi = fq >= 2;
      union { unsigned u[4]; short8 v; } pk;
      pk.u[0] = hi ? a2 : a0;
      pk.u[1] = hi ? a3 : a1;
      pk.u[2] = hi ? b2 : b0;
      pk.u[3] = hi ? b3 : b1;
      const short8 pa = pk.v;
      #pragma unroll
      for (int nf = 0; nf < 4; ++nf){
        const int d = (nf<<4) + fr;
        const short8 vf = *(const short8*)(vb + (d<<7) + (((fq ^ (d&7) ^ (d>>3)) & 7)<<4));
        oa[qt][nf] = __builtin_amdgcn_mfma_f32_16x16x32_bf16(pa, vf, oa[qt][nf], 0, 0, 0);
      }
    }

    if (st){
      asm volatile("s_waitcnt vmcnt(0)" ::: "memory");
      #pragma unroll
      for (int j = 0; j < 8; ++j){
        const int d = sg*8 + j;
        const int off = (d<<7) + ((((sr>>3) ^ j ^ sg) & 7) << 4) + ((sr&7)<<1);
        *(unsigned short*)((char*)&Vt[buf^1][0] + off) = ((const unsigned short*)&vv)[j];
      }
    }
    __syncthreads();
  }

  #pragma unroll
  for (int qt = 0; qt < 2; ++qt){
    const float rl = 1.f / ls_[qt];
    const float rA = __shfl(rl, (fq<<2)+0), rB = __shfl(rl, (fq<<2)+1);
    const float rC = __shfl(rl, (fq<<2)+2), rD = __shfl(rl, (fq<<2)+3);
    const size_t r0 = (size_t)(b*NP + qs*192 + (qt*6 + w)*16 + (fq<<2));
    #pragma unroll
    for (int nf = 0; nf < 4; ++nf){
      const int col = h*DHEAD + (nf<<4) + fr;
      o[(r0 + 0)*D_ + col] = f2bf(oa[qt][nf][0] * rA);
      o[(r0 + 1)*D_ + col] = f2bf(oa[qt][nf][1] * rB);
      o[(r0 + 2)*D_ + col] = f2bf(oa[qt][nf][2] * rC);
      o[(r0 + 3)*D_ + col] = f2bf(oa[qt][nf][3] * rD);
    }
  }
}

// ---------------- fused weight conversion (us8 stores, 16B/lane) -------------
// regions (8-float units): qkv 2654208 | wo 884736 | w1 3538944 | w2 3538944
__global__ void k_wconv(const float* __restrict__ Wq, const float* __restrict__ Wk,
                        const float* __restrict__ Wv, const float* __restrict__ Wo,
                        const float* __restrict__ W1, const float* __restrict__ W2,
                        unsigned short* __restrict__ wqkv, unsigned short* __restrict__ wo,
                        unsigned short* __restrict__ w1, unsigned short* __restrict__ w2){
  const long Q8 = 2654208, O8 = 884736, F8 = 3538944;
  const long n8 = Q8 + O8 + F8 + F8;
  long i = (long)blockIdx.x * blockDim.x + threadIdx.x;
  const long st = (long)gridDim.x * blockDim.x;
  for (; i < n8; i += st){
    const float* src;
    unsigned short* dst;
    long j;
    if (i < Q8){
      const int lay = (int)(i / (2304 * 96));
      const int rem = (int)(i % (2304 * 96));
      const int r = rem / 96, k8 = rem % 96;
      const float* s = (r < 768) ? Wq : ((r < 1536) ? Wk : Wv);
      const int rr = (r < 768) ? r : ((r < 1536) ? r - 768 : r - 1536);
      src = s + (size_t)lay * 589824 + (size_t)rr * 768 + k8*8;
      dst = wqkv; j = i;
    } else if (i < Q8 + O8){
      j = i - Q8; src = Wo + j*8; dst = wo;
    } else if (i < Q8 + O8 + F8){
      j = i - Q8 - O8; src = W1 + j*8; dst = w1;
    } else {
      j = i - Q8 - O8 - F8; src = W2 + j*8; dst = w2;
    }
    const float4v v0 = *(const float4v*)src;
    const float4v v1 = *(const float4v*)(src + 4);
    const us4 r0 = f2bf4(v0), r1 = f2bf4(v1);
    us8 o;
    o.s0 = r0.x; o.s1 = r0.y; o.s2 = r0.z; o.s3 = r0.w;
    o.s4 = r1.x; o.s5 = r1.y; o.s6 = r1.z; o.s7 = r1.w;
    *(us8*)(dst + j*8) = o;
  }
}

__global__ void k_pack_qkvb(const float* __restrict__ bq, const float* __restrict__ bk,
                            const float* __restrict__ bv, float* __restrict__ dst){
  const int i = blockIdx.x * 256 + threadIdx.x;
  if (i >= 12 * 2304) return;
  const int lay = i / 2304, r = i % 2304;
  const float* s = (r < 768) ? bq : ((r < 1536) ? bk : bv);
  const int rr = (r < 768) ? r : ((r < 1536) ? r - 768 : r - 1536);
  dst[i] = s[lay * 768 + rr];
}

__global__ void k_patchw(const float* __restrict__ s, unsigned short* __restrict__ d){
  const long n4 = (long)768 * (KPAT/4);
  long i = (long)blockIdx.x * blockDim.x + threadIdx.x;
  const long st = (long)gridDim.x * blockDim.x;
  for (; i < n4; i += st){
    const int r = (int)(i / (KPAT/4)), k4 = (int)(i % (KPAT/4));
    us4 o = {0,0,0,0};
    if (k4*4 < 1200)
      o = f2bf4(*(const float4v*)(s + (size_t)r * 1200 + k4*4));
    ((us4*)d)[i] = o;
  }
}

__global__ void k_patches(const float* __restrict__ x, unsigned short* __restrict__ d){
  const long n4 = (long)MROWS * (KPAT/4);
  long i = (long)blockIdx.x * blockDim.x + threadIdx.x;
  const long st = (long)gridDim.x * blockDim.x;
  for (; i < n4; i += st){
    const int mrow = (int)(i / (KPAT/4)), k4 = (int)(i % (KPAT/4));
    const int k = k4 * 4;
    us4 o = {0,0,0,0};
    if (k < 1200){
      const int c = k / 400, rem = k % 400, py = rem / 20, px = rem % 20;
      const int b = mrow / NP, pn = mrow % NP, hp = pn / 18, wp = pn % 18;
      const float4v v = *(const float4v*)(x + ((((size_t)b * 3 + c) * 640 + hp * 20 + py) * 360 + wp * 20 + px));
      o = f2bf4(v);
    }
    ((us4*)d)[i] = o;
  }
}

__global__ __launch_bounds__(256) void k_ln(float* h, unsigned short* hb,
                                            const float* __restrict__ g,
                                            const float* __restrict__ bt){
  const int r = blockIdx.x, t = threadIdx.x;
  const size_t base = (size_t)r * D_;
  const float x0 = h[base + t], x1 = h[base + t + 256], x2 = h[base + t + 512];
  float s = x0 + x1 + x2;
  #pragma unroll
  for (int o = 1; o < 64; o <<= 1) s += __shfl_xor(s, o);
  __shared__ float red[8];
  const int w = t >> 6, l = t & 63;
  if (l == 0) red[w] = s;
  __syncthreads();
  const float mu = (red[0] + red[1] + red[2] + red[3]) * (1.f / 768.f);
  const float d0 = x0 - mu, d1 = x1 - mu, d2 = x2 - mu;
  float v = d0*d0 + d1*d1 + d2*d2;
  #pragma unroll
  for (int o = 1; o < 64; o <<= 1) v += __shfl_xor(v, o);
  if (l == 0) red[4 + w] = v;
  __syncthreads();
  const float var = (red[4] + red[5] + red[6] + red[7]) * (1.f / 768.f);
  const float rs = rsqrtf(var + 1e-5f);
  const float y0 = d0 * rs * g[t]       + bt[t];
  const float y1 = d1 * rs * g[t + 256] + bt[t + 256];
  const float y2 = d2 * rs * g[t + 512] + bt[t + 512];
  h[base + t] = y0; h[base + t + 256] = y1; h[base + t + 512] = y2;
  hb[base + t] = f2bf(y0); hb[base + t + 256] = f2bf(y1); hb[base + t + 512] = f2bf(y2);
}

__global__ void k_pool(const float* __restrict__ h, float* __restrict__ p){
  const int i = blockIdx.x * 256 + threadIdx.x;   // 12288
  const int b = i / D_, c = i % D_;
  const float* base = h + (size_t)b * NP * D_ + c;
  float s = 0.f;
  for (int n = 0; n < NP; ++n) s += base[(size_t)n * D_];
  p[i] = s * (1.f / 576.f);
}

__global__ __launch_bounds__(64) void k_fc(const float* __restrict__ p, const float* __restrict__ w,
                                           const float* __restrict__ bias, float* __restrict__ out){
  const int oi = blockIdx.x;                       // 160
  const int b = oi / 10, j = oi % 10;
  const int l = threadIdx.x;
  float s = 0.f;
  for (int c = l; c < D_; c += 64) s += p[b * D_ + c] * w[j * D_ + c];
  #pragma unroll
  for (int o = 1; o < 64; o <<= 1) s += __shfl_xor(s, o);
  if (l == 0) out[oi] = s + bias[j];
}

// ---------------- launch ------------------------------------------------------
extern "C" void kernel_launch(void* const* d_in, const int* in_sizes, int n_in,
                              void* d_out, int out_size, void* d_ws, size_t ws_size,
                              hipStream_t stream)
{
  const float* x       = (const float*)d_in[0];
  const float* patch_w = (const float*)d_in[1];
  const float* patch_b = (const float*)d_in[2];
  const float* pos_emb = (const float*)d_in[3];
  const float* ln_g    = (const float*)d_in[4];
  const float* ln_b    = (const float*)d_in[5];
  const float* Wq      = (const float*)d_in[6];
  const float* bq      = (const float*)d_in[7];
  const float* Wk      = (const float*)d_in[8];
  const float* bk      = (const float*)d_in[9];
  const float* Wv      = (const float*)d_in[10];
  const float* bv      = (const float*)d_in[11];
  const float* Wo      = (const float*)d_in[12];
  const float* bo      = (const float*)d_in[13];
  const float* W1      = (const float*)d_in[14];
  const float* b1      = (const float*)d_in[15];
  const float* W2      = (const float*)d_in[16];
  const float* b2      = (const float*)d_in[17];
  const float* fc_w    = (const float*)d_in[18];
  const float* fc_b    = (const float*)d_in[19];
  float* out = (float*)d_out;
  (void)in_sizes; (void)n_in; (void)out_size; (void)ws_size;

  char* ws = (char*)d_ws;
  size_t off = 0;
  auto alloc = [&](size_t bytes) -> char* {
    char* p = ws + off;
    off += (bytes + 255) & ~(size_t)255;
    return p;
  };
  unsigned short* wqkv    = (unsigned short*)alloc((size_t)12*2304*768*2);
  unsigned short* wo      = (unsigned short*)alloc((size_t)12*768*768*2);
  unsigned short* w1      = (unsigned short*)alloc((size_t)12*3072*768*2);
  unsigned short* w2      = (unsigned short*)alloc((size_t)12*768*3072*2);
  unsigned short* wp      = (unsigned short*)alloc((size_t)768*KPAT*2);
  float*          bqkv    = (float*)alloc((size_t)12*2304*4);
  unsigned short* patches = (unsigned short*)alloc((size_t)MROWS*KPAT*2);
  float*          hf      = (float*)alloc((size_t)MROWS*D_*4);
  unsigned short* hb      = (unsigned short*)alloc((size_t)MROWS*D_*2);
  unsigned short* qkvb    = (unsigned short*)alloc((size_t)MROWS*2304*2);
  unsigned short* ob      = (unsigned short*)alloc((size_t)MROWS*D_*2);
  unsigned short* ffb     = (unsigned short*)alloc((size_t)MROWS*3072*2);
  float*          pooled  = (float*)alloc((size_t)16*D_*4);

  // weight conversion / packing (bf16), fused + 16B stores
  k_wconv<<<4096, 256, 0, stream>>>(Wq, Wk, Wv, Wo, W1, W2, wqkv, wo, w1, w2);
  k_pack_qkvb<<<(12*2304 + 255)/256, 256, 0, stream>>>(bq, bk, bv, bqkv);
  k_patchw<<<2048, 256, 0, stream>>>(patch_w, wp);
  k_patches<<<2048, 256, 0, stream>>>(x, patches);

  // patch embed (+bias +pos) -> hf ; LN -> hf (in-place) + hb
  gemm34<<<72*6, 512, 0, stream>>>(patches, wp, patch_b, pos_emb,
                                   nullptr, hf, nullptr, MROWS, 768, KPAT, 0);
  k_ln<<<MROWS, 256, 0, stream>>>(hf, hb, ln_g, ln_b);

  for (int l = 0; l < 12; ++l){
    gemm3r<<<36*18, 512, 0, stream>>>(hb, wqkv + (size_t)l*2304*768, bqkv + l*2304,
                                      nullptr, nullptr, nullptr, qkvb, MROWS, 2304, 768, 0);
    k_attn<<<576, 384, 0, stream>>>(qkvb, ob);
    gemm34<<<72*6, 512, 0, stream>>>(ob, wo + (size_t)l*768*768, bo + l*768,
                                     nullptr, hf, hf, hb, MROWS, 768, 768, 0);
    gemm3r<<<36*24, 512, 0, stream>>>(hb, w1 + (size_t)l*3072*768, b1 + (size_t)l*3072,
                                      nullptr, nullptr, nullptr, ffb, MROWS, 3072, 768, 1);
    gemm34<<<72*6, 512, 0, stream>>>(ffb, w2 + (size_t)l*768*3072, b2 + l*768,
                                     nullptr, hf, hf, hb, MROWS, 768, 3072, 0);
  }
  k_pool<<<48, 256, 0, stream>>>(hf, pooled);
  k_fc<<<160, 64, 0, stream>>>(pooled, fc_w, fc_b, out);
}